// Round 14
// baseline (1784.457 us; speedup 1.0000x reference)
//
#include <hip/hip_runtime.h>
#include <hip/hip_fp16.h>

// ---------------------------------------------------------------------------
// BiLSTM(70) -> BiLSTM(21) -> MLP head. B=512 T=1024 F=8.
//
// R16 (= R15 with compile fix): pre2 GEMM FUSED into lstm1 (pre2 kernel
//      deleted). Each lstm1 block, one step behind the recurrence, computes
//      its direction's half-K contribution P_d[n][batch] = W2_d x km-h for
//      ALL 168 output cols, reusing the SAME B-fragments (bf0..bf2) already
//      loaded for the layer-1 tiles (W2 packed with zeros at x cols k<8,
//      bias col 78, k>=80). 11 W2 tiles ride on waves w2..w12 (+3 MFMA
//      each, zero extra LDS reads / trans). Halves combine via
//      unsafeAtomicAdd(__half2) (global_atomic_pk_add_f16; ws is coarse-
//      grained) onto a hipMemsetAsync-zeroed pre buffer; fwd adds bias via
//      MFMA C-in. Compute waves never wait vmcnt (LDS-only barrier doesn't
//      drain atomics). Epilogue handles the last timestep. lstm2 (8-deep
//      prefetch, DPP, setprio) and head unchanged from R14 (1201us).
// ---------------------------------------------------------------------------

typedef _Float16 v2f16 __attribute__((ext_vector_type(2)));
typedef _Float16 v4h   __attribute__((ext_vector_type(4)));
typedef _Float16 v8h   __attribute__((ext_vector_type(8)));
typedef float    f32x4 __attribute__((ext_vector_type(4)));

__device__ __forceinline__ float fdot2(v2f16 a, v2f16 b, float c) {
  return __builtin_amdgcn_fdot2(a, b, c, false);
}
#if __has_builtin(__builtin_amdgcn_rcpf)
__device__ __forceinline__ float rcpf(float x) { return __builtin_amdgcn_rcpf(x); }
#else
__device__ __forceinline__ float rcpf(float x) { return 1.f / x; }
#endif
// raw 2^x (weights pre-scaled by log2e so activations need no mul)
__device__ __forceinline__ float ex2(float v) {
#if __has_builtin(__builtin_amdgcn_exp2f)
  return __builtin_amdgcn_exp2f(v);
#else
  return __expf(v * 0.6931471805599453f);
#endif
}
// xor lane-bit-0 exchange via DPP quad_perm [1,0,3,2] (1 VALU op, no LDS)
__device__ __forceinline__ float dpp_xor1(float v) {
  return __builtin_bit_cast(float,
      __builtin_amdgcn_update_dpp(0, __builtin_bit_cast(int, v),
                                  0xB1 /*quad_perm 1,0,3,2*/, 0xF, 0xF, true));
}
// packed fp16 atomic add (global_atomic_pk_add_f16). Workspace is
// coarse-grained device memory -> unsafeAtomicAdd lowers to the HW op.
__device__ __forceinline__ void atom_pk_add(_Float16* p, float v0, float v1) {
  v2f16 t; t[0] = (_Float16)v0; t[1] = (_Float16)v1;
  unsafeAtomicAdd(reinterpret_cast<__half2*>(p), __builtin_bit_cast(__half2, t));
}

// LDS-only workgroup barrier: orders DS ops across waves WITHOUT draining
// vmcnt (global loads/stores/atomics stay in flight across steps).
__device__ __forceinline__ void lds_barrier() {
  asm volatile("s_waitcnt lgkmcnt(0)" ::: "memory");
  __builtin_amdgcn_s_barrier();
  __builtin_amdgcn_sched_barrier(0);
}

#define LOG2E  1.4426950408889634f
#define LOG2E2 2.8853900817779268f

// workspace offsets (bytes)
#define O_W1M  0u         // [2][288][96] fp16 = 110592 (lstm1 A, row=u*4+g, K: x8|h70|pad|bias@78, log2e-scaled)
#define O_WP2  110592u    // [2][84][24]  fp16 = 8064   (lstm2 fdot W, row=g*21+u, log2e-scaled)
#define O_W2F  118656u    // [2][176][96] fp16 = 67584  (fused-pre2 A: dir d's half-K; k<8,78,79+ zero; log2e-scaled)
#define O_BIAS 186240u    // [176] f32    = 704         (log2e-scaled, unit-major)
#define O_DATA 186944u    // pre [rows][176] fp16, then h2 [rows][48] fp16

// ---------------------------------------------------------------------------
// K0: pack all weights.
// ---------------------------------------------------------------------------
__global__ void pack_kernel(const float* __restrict__ wihf, const float* __restrict__ whhf,
                            const float* __restrict__ wihb, const float* __restrict__ whhb,
                            const float* __restrict__ b1if, const float* __restrict__ b1hf,
                            const float* __restrict__ b1ib, const float* __restrict__ b1hb,
                            const float* __restrict__ wih2f, const float* __restrict__ wih2b,
                            const float* __restrict__ whh2f, const float* __restrict__ whh2b,
                            const float* __restrict__ bif, const float* __restrict__ bhf,
                            const float* __restrict__ bib, const float* __restrict__ bhb,
                            char* __restrict__ ws) {
  _Float16* w1m = (_Float16*)(ws + O_W1M);
  _Float16* wp2 = (_Float16*)(ws + O_WP2);
  _Float16* w2f = (_Float16*)(ws + O_W2F);
  float* biasc = (float*)(ws + O_BIAS);
  int idx = blockIdx.x * 256 + threadIdx.x;
  if (idx < 55296) {  // w1m: [d][288 rows (u*4+g)][96 k], log2e-scaled
    int d = idx / 27648, rem = idx % 27648, rp = rem / 96, k = rem % 96;
    int u = rp >> 2, g = rp & 3;
    const float* wih = d ? wihb : wihf;
    const float* whh = d ? whhb : whhf;
    const float* bi = d ? b1ib : b1if;
    const float* bh = d ? b1hb : b1hf;
    float v = 0.f;
    if (u < 70) {
      int src = g * 70 + u;
      float scale = (g == 2) ? LOG2E2 : LOG2E;
      if (k < 8) v = wih[src * 8 + k] * scale;
      else if (k < 78) v = whh[src * 70 + (k - 8)] * scale;
      else if (k == 78) v = (bi[src] + bh[src]) * scale;
    }
    w1m[idx] = (_Float16)v;
  } else if (idx < 59328) {  // wp2: [d][84 rows g*21+u][24 k], log2e-scaled
    int j = idx - 55296;
    int d = j / 2016, rem = j % 2016, r = rem / 24, k = rem % 24;
    const float* whh = d ? whh2b : whh2f;
    float scale = (r / 21 == 2) ? LOG2E2 : LOG2E;
    wp2[j] = (_Float16)((k < 21) ? whh[r * 21 + k] * scale : 0.f);
  } else if (idx < 93120) {  // w2f: [dd lstm1-dir][176 n][96 k], K-window = km cols
    int j = idx - 59328;  // < 33792
    int dd = j / 16896, rem = j % 16896, n = rem / 96, k = rem % 96;
    float v = 0.f;
    if (n < 168 && k >= 8 && k < 78) {
      int d2 = n / 84, m = n % 84, u = m >> 2, g = m & 3;
      const float* wih = d2 ? wih2b : wih2f;
      float scale = (g == 2) ? LOG2E2 : LOG2E;
      v = wih[(g * 21 + u) * 140 + dd * 70 + (k - 8)] * scale;
    }
    w2f[j] = (_Float16)v;
  } else if (idx < 93296) {  // biasc[176], scaled, unit-major order
    int n = idx - 93120;
    float v = 0.f;
    if (n < 168) {
      int d = n / 84, m = n % 84, u = m >> 2, g = m & 3;
      const float* bi = d ? bib : bif;
      const float* bh = d ? bhb : bhf;
      float scale = (g == 2) ? LOG2E2 : LOG2E;
      v = (bi[g * 21 + u] + bh[g * 21 + u]) * scale;
    }
    biasc[n] = v;
  }
}

// ---------------------------------------------------------------------------
// K1: layer-1 LSTM on MFMA + fused pre2. Block = 16 batches x 1 dir, 1024
// threads (16 waves). L1 tiles: w0,w1 -> 2 (T=2w,2w+1); w2-13 -> 1 (T=w+2);
// w14 -> 2 (T=16,17); w15 -> 0 (pure x-loader wave, 4-deep reg pipeline,
// vmcnt-isolated). W2 tiles Tw=0..10 on waves w2..w12, reusing bf0..bf2
// (same K-window; km cols 79..103 stay zero, col 78=1.0 hits zero weights).
// W2 product lags one step (km[cur] h = h(te(s-1))); atomic pk_add into
// pre; fwd block carries bias as MFMA C-in. Epilogue covers te(1023).
// Merged-rcp GATE (8 trans). One LDS-only barrier/step.
// ---------------------------------------------------------------------------
__global__ __launch_bounds__(1024) void lstm1_kernel(
    const float* __restrict__ x,
    const _Float16* __restrict__ w1m,
    const _Float16* __restrict__ w2f,
    const float* __restrict__ biasc,
    _Float16* __restrict__ pre, int b0, int nb) {
  __shared__ __align__(16) _Float16 km[2][16][104];
  const int tid = threadIdx.x;
  const int w = tid >> 6, lane = tid & 63;
  const int q = lane >> 4, bc = lane & 15;
  const int d = blockIdx.y;
  const int blg = blockIdx.x * 16;   // slice-local batch base
  const int gb0 = b0 + blg;          // global batch base (for x)

  for (int i = tid; i < 2 * 16 * 104; i += 1024) ((_Float16*)km)[i] = (_Float16)0.f;

  const bool ldr = (w == 15);
  const bool two = (w < 2) || (w == 14);
  const int T0 = (w < 2) ? 2 * w : (w == 14 ? 16 : w + 2);

  // L1 A-fragments: up to 2 tiles x 3 K-chunks (bias folded at k=78)
  v8h af[2][3];
  if (!ldr) {
#pragma unroll
    for (int kc = 0; kc < 3; ++kc)
      af[0][kc] = *(const v8h*)&w1m[(size_t)(d * 288 + T0 * 16 + bc) * 96 + kc * 32 + q * 8];
    if (two) {
#pragma unroll
      for (int kc = 0; kc < 3; ++kc)
        af[1][kc] = *(const v8h*)&w1m[(size_t)(d * 288 + (T0 + 1) * 16 + bc) * 96 + kc * 32 + q * 8];
    }
  }

  // W2 (fused pre2) setup: tiles on w2..w12
  const bool w2w = (w >= 2 && w <= 12);
  const int Tw = w - 2;
  const int n0 = Tw * 16 + q * 4;
  const bool w2st = w2w && (n0 < 168);  // rows n0..n0+3 valid (168 = 42*4)
  v8h wf0, wf1, wf2;
  f32x4 pbias = (f32x4){0.f, 0.f, 0.f, 0.f};
  if (w2w) {
    wf0 = *(const v8h*)&w2f[(size_t)(d * 176 + Tw * 16 + bc) * 96 + 0 * 32 + q * 8];
    wf1 = *(const v8h*)&w2f[(size_t)(d * 176 + Tw * 16 + bc) * 96 + 1 * 32 + q * 8];
    wf2 = *(const v8h*)&w2f[(size_t)(d * 176 + Tw * 16 + bc) * 96 + 2 * 32 + q * 8];
    if (d == 0 && n0 < 168) {
      pbias[0] = biasc[n0];     pbias[1] = biasc[n0 + 1];
      pbias[2] = biasc[n0 + 2]; pbias[3] = biasc[n0 + 3];
    }
  }

  __syncthreads();  // zero-init done before targeted writes below

  if (tid < 16) {  // constant-1.0 column for bias
    km[0][tid][78] = (_Float16)1.f;
    km[1][tid][78] = (_Float16)1.f;
  }
  const bool xlane = ldr && (lane < 32);  // wave 15 lanes 0..31
  const int xb = lane >> 1, xhalf = lane & 1;
  // x for step s lives at t(s) = d ? 1023-s : s
  float4 xa, xb4, xc, xd;            // x for steps s+1..s+4
  const float* xp = nullptr;         // -> t(s+5) element, advanced per step
  const ptrdiff_t xstep = d ? -8 : 8;
  if (xlane) {
    const float* xrow = &x[((size_t)(gb0 + xb) * 1024) * 8 + xhalf * 4];
    int t0 = d ? 1023 : 0;
    float4 xv = *(const float4*)&xrow[(size_t)t0 * 8];
    v4h xh; xh[0] = (_Float16)xv.x; xh[1] = (_Float16)xv.y;
    xh[2] = (_Float16)xv.z; xh[3] = (_Float16)xv.w;
    *(v4h*)&km[0][xb][xhalf * 4] = xh;
    xa  = *(const float4*)&xrow[(size_t)(d ? 1022 : 1) * 8];
    xb4 = *(const float4*)&xrow[(size_t)(d ? 1021 : 2) * 8];
    xc  = *(const float4*)&xrow[(size_t)(d ? 1020 : 3) * 8];
    xd  = *(const float4*)&xrow[(size_t)(d ? 1019 : 4) * 8];
    xp  = &xrow[(size_t)(d ? 1018 : 5) * 8];
  }
  float c0 = 0.f, c1 = 0.f;
  int s = 0;
  __syncthreads();

  // preacts log2e-scaled (g by 2log2e): e = 2^-A. Merged-rcp forms:
  // si*tanh_g = (1-eg)/((1+ei)(1+eg)); so*tanh_c = (1-ec)/((1+eo)(1+ec)),
  // tanh-c exp input clamped so ec stays finite.
#define GATE(Ai, ci, U)                                                      \
    {                                                                        \
      float ei = ex2(-Ai[0]);                                                \
      float ef = ex2(-Ai[1]);                                                \
      float eg = ex2(-Ai[2]);                                                \
      float eo = ex2(-Ai[3]);                                                \
      float sf = rcpf(1.f + ef);                                             \
      float ig = (1.f - eg) * rcpf((1.f + ei) * (1.f + eg));                 \
      ci = fmaf(sf, ci, ig);                                                 \
      float cl = fminf(fmaxf(ci, -14.f), 14.f);                              \
      float ec = ex2(cl * -LOG2E2);                                          \
      float hv = (1.f - ec) * rcpf((1.f + eo) * (1.f + ec));                 \
      if ((U) < 70) km[nxt][bc][8 + (U)] = (_Float16)hv;                     \
    }

#define STEP1(XR)                                                            \
  {                                                                          \
    const int cur = s & 1, nxt = cur ^ 1;                                    \
    if (!ldr) {                                                              \
      v8h bf0 = *(const v8h*)&km[cur][bc][q * 8];                            \
      v8h bf1 = *(const v8h*)&km[cur][bc][32 + q * 8];                       \
      v8h bf2 = *(const v8h*)&km[cur][bc][64 + q * 8];                       \
      f32x4 z4 = (f32x4){0.f, 0.f, 0.f, 0.f};                                \
      f32x4 A0 = __builtin_amdgcn_mfma_f32_16x16x32_f16(af[0][0], bf0, z4, 0, 0, 0); \
      f32x4 A1 = z4;                                                         \
      if (two) A1 = __builtin_amdgcn_mfma_f32_16x16x32_f16(af[1][0], bf0, z4, 0, 0, 0); \
      A0 = __builtin_amdgcn_mfma_f32_16x16x32_f16(af[0][1], bf1, A0, 0, 0, 0); \
      if (two) A1 = __builtin_amdgcn_mfma_f32_16x16x32_f16(af[1][1], bf1, A1, 0, 0, 0); \
      A0 = __builtin_amdgcn_mfma_f32_16x16x32_f16(af[0][2], bf2, A0, 0, 0, 0); \
      if (two) A1 = __builtin_amdgcn_mfma_f32_16x16x32_f16(af[1][2], bf2, A1, 0, 0, 0); \
      if (w2st && s > 0) {  /* pre2 contribution for h(te(s-1)) */           \
        f32x4 Pv = pbias;                                                    \
        Pv = __builtin_amdgcn_mfma_f32_16x16x32_f16(wf0, bf0, Pv, 0, 0, 0);  \
        Pv = __builtin_amdgcn_mfma_f32_16x16x32_f16(wf1, bf1, Pv, 0, 0, 0);  \
        Pv = __builtin_amdgcn_mfma_f32_16x16x32_f16(wf2, bf2, Pv, 0, 0, 0);  \
        int tp = d ? (1024 - s) : (s - 1);                                   \
        _Float16* pq = &pre[((size_t)tp * nb + blg + bc) * 176 + n0];        \
        atom_pk_add(pq, Pv[0], Pv[1]);                                       \
        atom_pk_add(pq + 2, Pv[2], Pv[3]);                                   \
      }                                                                      \
      GATE(A0, c0, T0 * 4 + q)                                               \
      if (two) GATE(A1, c1, (T0 + 1) * 4 + q)                                \
    } else if (xlane) {                                                      \
      if (s < 1023) {                                                        \
        v4h xh; xh[0] = (_Float16)XR.x; xh[1] = (_Float16)XR.y;              \
        xh[2] = (_Float16)XR.z; xh[3] = (_Float16)XR.w;                      \
        *(v4h*)&km[nxt][xb][xhalf * 4] = xh;                                 \
      }                                                                      \
      if (s <= 1018) XR = *(const float4*)xp;                                \
      xp += xstep;                                                           \
    }                                                                        \
    ++s;                                                                     \
    lds_barrier();                                                           \
  }

#pragma unroll 1
  for (int it = 0; it < 256; ++it) {
    STEP1(xa)
    STEP1(xb4)
    STEP1(xc)
    STEP1(xd)
  }
#undef STEP1
#undef GATE

  // epilogue: pre2 contribution for the final h(te(1023)), now in km[0]
  if (w2st) {
    v8h bf0 = *(const v8h*)&km[0][bc][q * 8];
    v8h bf1 = *(const v8h*)&km[0][bc][32 + q * 8];
    v8h bf2 = *(const v8h*)&km[0][bc][64 + q * 8];
    f32x4 Pv = pbias;
    Pv = __builtin_amdgcn_mfma_f32_16x16x32_f16(wf0, bf0, Pv, 0, 0, 0);
    Pv = __builtin_amdgcn_mfma_f32_16x16x32_f16(wf1, bf1, Pv, 0, 0, 0);
    Pv = __builtin_amdgcn_mfma_f32_16x16x32_f16(wf2, bf2, Pv, 0, 0, 0);
    int tp = d ? 0 : 1023;
    _Float16* pq = &pre[((size_t)tp * nb + blg + bc) * 176 + n0];
    atom_pk_add(pq, Pv[0], Pv[1]);
    atom_pk_add(pq + 2, Pv[2], Pv[3]);
  }
}

// ---------------------------------------------------------------------------
// K3: layer-2 LSTM, ONE 64-lane wave per (batch, dir). lane = u*2+p, u<21:
// lane computes gate rows {2p, 2p+1} (12 fdot2 each, 4-way split chains);
// quad completed by ONE DPP quad_perm exchange. NO barriers (single wave).
// pre preacts: unit-major -> lane's gate pair is one v2f16 load, prefetched
// EIGHT steps deep. s_setprio(1) around the dot+act region. Weights and
// preacts log2e-scaled -> raw exp2. h2 row = t*nb+bl, stride 48.
// ---------------------------------------------------------------------------
__global__ __launch_bounds__(64) void lstm2_kernel(
    const _Float16* __restrict__ pre2, const _Float16* __restrict__ wp2,
    _Float16* __restrict__ h2, int nb) {
  __shared__ __align__(16) _Float16 kv[2][32];  // [buf][ 0..20 h | 21..31 zero ]
  const int lane = threadIdx.x;
  const int bl = blockIdx.x;
  const int d = blockIdx.y;
  const int u = lane >> 1, p = lane & 1;
  const bool active = lane < 42;

  ((_Float16*)kv)[lane] = (_Float16)0.f;  // 64 entries, 64 lanes

  v2f16 w0[12], w1[12];
  if (active) {
    const v8h* wr0 = (const v8h*)&wp2[(d * 84 + (2 * p) * 21 + u) * 24];
    const v8h* wr1 = (const v8h*)&wp2[(d * 84 + (2 * p + 1) * 21 + u) * 24];
#pragma unroll
    for (int ch = 0; ch < 3; ++ch) {
      v8h a = wr0[ch], b = wr1[ch];
#pragma unroll
      for (int q = 0; q < 4; ++q) {
        v2f16 t0; t0[0] = a[2 * q]; t0[1] = a[2 * q + 1]; w0[ch * 4 + q] = t0;
        v2f16 t1; t1[0] = b[2 * q]; t1[1] = b[2 * q + 1]; w1[ch * 4 + q] = t1;
      }
    }
  }
  // unit-major pre: gates (2p, 2p+1) of unit u are ADJACENT columns
  const int cp = d * 84 + u * 4 + 2 * p;
  const ptrdiff_t dlt = (ptrdiff_t)(d ? -nb : nb) * 176;
  const _Float16* pp = pre2 + ((size_t)(d ? 1023 : 0) * (size_t)nb + bl) * 176;

  // 8-deep prefetch pipeline: one v2f16 per step
  v2f16 pa = *(const v2f16*)(pp + cp);
  v2f16 pb = *(const v2f16*)(pp + dlt + cp);
  v2f16 pc = *(const v2f16*)(pp + 2 * dlt + cp);
  v2f16 pd = *(const v2f16*)(pp + 3 * dlt + cp);
  v2f16 pe = *(const v2f16*)(pp + 4 * dlt + cp);
  v2f16 pg = *(const v2f16*)(pp + 5 * dlt + cp);
  v2f16 ph = *(const v2f16*)(pp + 6 * dlt + cp);
  v2f16 pi = *(const v2f16*)(pp + 7 * dlt + cp);
  const _Float16* pf = pp + 8 * dlt;

  float cc = 0.f;
  int s = 0;

#define L2STEP(P)                                                           \
  {                                                                         \
    const int cur = s & 1, nxt = cur ^ 1;                                   \
    float A0v = (float)P[0], A1v = (float)P[1];                             \
    const float4* kp = (const float4*)&kv[cur][0];                          \
    float4 q0 = kp[0], q1 = kp[1], q2 = kp[2];                              \
    __builtin_amdgcn_s_setprio(1);                                          \
    float x0 = A0v, x1 = 0.f, x2 = 0.f, x3 = 0.f;                           \
    float z0 = A1v, z1 = 0.f, z2 = 0.f, z3 = 0.f;                           \
    x0 = fdot2(__builtin_bit_cast(v2f16, q0.x), w0[0], x0);                 \
    x1 = fdot2(__builtin_bit_cast(v2f16, q0.y), w0[1], x1);                 \
    x2 = fdot2(__builtin_bit_cast(v2f16, q0.z), w0[2], x2);                 \
    x3 = fdot2(__builtin_bit_cast(v2f16, q0.w), w0[3], x3);                 \
    x0 = fdot2(__builtin_bit_cast(v2f16, q1.x), w0[4], x0);                 \
    x1 = fdot2(__builtin_bit_cast(v2f16, q1.y), w0[5], x1);                 \
    x2 = fdot2(__builtin_bit_cast(v2f16, q1.z), w0[6], x2);                 \
    x3 = fdot2(__builtin_bit_cast(v2f16, q1.w), w0[7], x3);                 \
    x0 = fdot2(__builtin_bit_cast(v2f16, q2.x), w0[8], x0);                 \
    x1 = fdot2(__builtin_bit_cast(v2f16, q2.y), w0[9], x1);                 \
    x2 = fdot2(__builtin_bit_cast(v2f16, q2.z), w0[10], x2);                \
    x3 = fdot2(__builtin_bit_cast(v2f16, q2.w), w0[11], x3);                \
    z0 = fdot2(__builtin_bit_cast(v2f16, q0.x), w1[0], z0);                 \
    z1 = fdot2(__builtin_bit_cast(v2f16, q0.y), w1[1], z1);                 \
    z2 = fdot2(__builtin_bit_cast(v2f16, q0.z), w1[2], z2);                 \
    z3 = fdot2(__builtin_bit_cast(v2f16, q0.w), w1[3], z3);                 \
    z0 = fdot2(__builtin_bit_cast(v2f16, q1.x), w1[4], z0);                 \
    z1 = fdot2(__builtin_bit_cast(v2f16, q1.y), w1[5], z1);                 \
    z2 = fdot2(__builtin_bit_cast(v2f16, q1.z), w1[6], z2);                 \
    z3 = fdot2(__builtin_bit_cast(v2f16, q1.w), w1[7], z3);                 \
    z0 = fdot2(__builtin_bit_cast(v2f16, q2.x), w1[8], z0);                 \
    z1 = fdot2(__builtin_bit_cast(v2f16, q2.y), w1[9], z1);                 \
    z2 = fdot2(__builtin_bit_cast(v2f16, q2.z), w1[10], z2);                \
    z3 = fdot2(__builtin_bit_cast(v2f16, q2.w), w1[11], z3);                \
    float A = (x0 + x1) + (x2 + x3), Bv = (z0 + z1) + (z2 + z3);            \
    /* row0 = gate 2p (p=0: i sigm, p=1: g tanh); row1 = f/o sigm */        \
    float r0v = rcpf(1.f + ex2(-A));                                        \
    float Y0 = p ? fmaf(2.f, r0v, -1.f) : r0v;                              \
    float Y1 = rcpf(1.f + ex2(-Bv));                                        \
    float Zs = dpp_xor1(Y0);                                                \
    float Ws = dpp_xor1(Y1);                                                \
    float ai = p ? Zs : Y0;                                                 \
    float af = p ? Ws : Y1;                                                 \
    float ag = p ? Y0 : Zs;                                                 \
    float ao = p ? Y1 : Ws;                                                 \
    cc = fmaf(af, cc, ai * ag);                                             \
    float tc = fmaf(2.f, rcpf(1.f + ex2(cc * -LOG2E2)), -1.f);              \
    float hv = ao * tc;                                                     \
    __builtin_amdgcn_s_setprio(0);                                          \
    if (active && p == 0) {                                                 \
      _Float16 hh = (_Float16)hv;                                           \
      int te = d ? (1023 - s) : s;                                          \
      kv[nxt][u] = hh;                                                      \
      h2[((size_t)te * nb + bl) * 48 + d * 21 + u] = hh;                    \
    }                                                                       \
    if (s < 1016) P = *(const v2f16*)(pf + cp);                             \
    pf += dlt;                                                              \
    ++s;                                                                    \
  }

#pragma unroll 1
  for (int it = 0; it < 128; ++it) {
    L2STEP(pa)
    L2STEP(pb)
    L2STEP(pc)
    L2STEP(pd)
    L2STEP(pe)
    L2STEP(pg)
    L2STEP(ph)
    L2STEP(pi)
  }
#undef L2STEP
}

// ---------------------------------------------------------------------------
// K4: dense head. local row = t*nb+bl -> out[(b0+bl)*1024 + t].
// ---------------------------------------------------------------------------
__global__ __launch_bounds__(256) void head_kernel(
    const _Float16* __restrict__ h2,
    const float* __restrict__ d1w, const float* __restrict__ d1b,
    const float* __restrict__ d2w, const float* __restrict__ d2b,
    const float* __restrict__ ow, const float* __restrict__ ob,
    float* __restrict__ out, int b0, int lognb) {
  int n = blockIdx.x * 256 + threadIdx.x;
  int t = n >> lognb, bl = n & ((1 << lognb) - 1);
  const v8h* hp = (const v8h*)&h2[(size_t)n * 48];
  float in[48];
#pragma unroll
  for (int i = 0; i < 6; ++i) {
    v8h hc = hp[i];
#pragma unroll
    for (int j = 0; j < 8; ++j) in[i * 8 + j] = (float)hc[j];
  }
  float a1[30];
#pragma unroll
  for (int cc = 0; cc < 30; ++cc) {
    float a = d1b[cc];
#pragma unroll
    for (int k = 0; k < 42; ++k) a += in[k] * d1w[cc * 42 + k];
    a1[cc] = fmaxf(a, 0.f);
  }
  float a2[20];
#pragma unroll
  for (int cc = 0; cc < 20; ++cc) {
    float a = d2b[cc];
#pragma unroll
    for (int k = 0; k < 30; ++k) a += a1[k] * d2w[cc * 30 + k];
    a2[cc] = fmaxf(a, 0.f);
  }
  float o = ob[0];
#pragma unroll
  for (int k = 0; k < 20; ++k) o += a2[k] * ow[k];
  out[(size_t)(b0 + bl) * 1024 + t] = o;
}

// ---------------------------------------------------------------------------
extern "C" void kernel_launch(void* const* d_in, const int* in_sizes, int n_in,
                              void* d_out, int out_size, void* d_ws, size_t ws_size,
                              hipStream_t stream) {
  const float* x = (const float*)d_in[0];
  const float* wih1f = (const float*)d_in[1];
  const float* whh1f = (const float*)d_in[2];
  const float* bih1f = (const float*)d_in[3];
  const float* bhh1f = (const float*)d_in[4];
  const float* wih1b = (const float*)d_in[5];
  const float* whh1b = (const float*)d_in[6];
  const float* bih1b = (const float*)d_in[7];
  const float* bhh1b = (const float*)d_in[8];
  const float* wih2f = (const float*)d_in[9];
  const float* whh2f = (const float*)d_in[10];
  const float* bih2f = (const float*)d_in[11];
  const float* bhh2f = (const float*)d_in[12];
  const float* wih2b = (const float*)d_in[13];
  const float* whh2b = (const float*)d_in[14];
  const float* bih2b = (const float*)d_in[15];
  const float* bhh2b = (const float*)d_in[16];
  const float* d1w = (const float*)d_in[17];
  const float* d1b = (const float*)d_in[18];
  const float* d2w = (const float*)d_in[19];
  const float* d2b = (const float*)d_in[20];
  const float* ow = (const float*)d_in[21];
  const float* ob = (const float*)d_in[22];
  float* out = (float*)d_out;
  char* wsb = (char*)d_ws;

  // adaptive batch slicing: per-slice bytes = rows*(352 + 96), rows = nb*1024
  const int cands[6] = {1, 2, 4, 8, 16, 32};
  int nslice = 32;
  for (int i = 0; i < 6; ++i) {
    size_t rows = (size_t)(512 / cands[i]) * 1024;
    if (O_DATA + rows * 448 <= ws_size) { nslice = cands[i]; break; }
  }
  const int nb = 512 / nslice;
  int lognb = 0; while ((1 << lognb) < nb) ++lognb;
  const size_t rows = (size_t)nb * 1024;

  _Float16* w1m = (_Float16*)(wsb + O_W1M);
  _Float16* wp2 = (_Float16*)(wsb + O_WP2);
  _Float16* w2f = (_Float16*)(wsb + O_W2F);
  const float* biasc = (const float*)(wsb + O_BIAS);
  _Float16* pre = (_Float16*)(wsb + O_DATA);          // fused preacts (atomic-summed)
  _Float16* h2  = (_Float16*)(wsb + O_DATA + rows * 352);

  pack_kernel<<<365, 256, 0, stream>>>(wih1f, whh1f, wih1b, whh1b,
                                       bih1f, bhh1f, bih1b, bhh1b,
                                       wih2f, wih2b, whh2f, whh2b,
                                       bih2f, bhh2f, bih2b, bhh2b, wsb);

  for (int s = 0; s < nslice; ++s) {
    const int b0 = s * nb;
    (void)hipMemsetAsync(pre, 0, rows * 352, stream);  // zero for atomics
    lstm1_kernel<<<dim3(nb / 16, 2), 1024, 0, stream>>>(x, w1m, w2f, biasc,
                                                        pre, b0, nb);
    lstm2_kernel<<<dim3(nb, 2), 64, 0, stream>>>(pre, wp2, h2, nb);
    head_kernel<<<nb * 4, 256, 0, stream>>>(h2, d1w, d1b, d2w, d2b, ow, ob,
                                            out, b0, lognb);
  }
}

// Round 15
// 1237.009 us; speedup vs baseline: 1.4426x; 1.4426x over previous
//
#include <hip/hip_runtime.h>

// ---------------------------------------------------------------------------
// BiLSTM(70) -> BiLSTM(21) -> MLP head. B=512 T=1024 F=8.
//
// R17: revert R16's fused-atomic pre2 (721MB RMW traffic, lstm1 600->1271).
//      Back to R14 structure (1201us best) with ONE lstm2 change: the kv
//      LDS round-trip (~120cy lgkm in the serial c-chain) is replaced by an
//      in-register broadcast -- both lanes of a unit pair compute identical
//      hv; quad_perm[2,3,0,1] DPP packs (h[2j],h[2j+1]) in lane 4j; 11
//      readlanes lift the 21-value h vector to wave-uniform dwords used
//      directly as fdot2 src0. lstm2 now uses ZERO LDS; 22 fdot2/step
//      (k-pair 11 dropped, weights there are zero). Pair-10 high half reads
//      lane40's zero-extended own value (never inactive-lane garbage).
//      lstm1 (16 waves + dedicated x-loader), pre2, head = R14 verbatim.
// ---------------------------------------------------------------------------

typedef _Float16 v2f16 __attribute__((ext_vector_type(2)));
typedef _Float16 v4h   __attribute__((ext_vector_type(4)));
typedef _Float16 v8h   __attribute__((ext_vector_type(8)));
typedef float    f32x4 __attribute__((ext_vector_type(4)));

__device__ __forceinline__ float fdot2(v2f16 a, v2f16 b, float c) {
  return __builtin_amdgcn_fdot2(a, b, c, false);
}
#if __has_builtin(__builtin_amdgcn_rcpf)
__device__ __forceinline__ float rcpf(float x) { return __builtin_amdgcn_rcpf(x); }
#else
__device__ __forceinline__ float rcpf(float x) { return 1.f / x; }
#endif
// raw 2^x (weights pre-scaled by log2e so activations need no mul)
__device__ __forceinline__ float ex2(float v) {
#if __has_builtin(__builtin_amdgcn_exp2f)
  return __builtin_amdgcn_exp2f(v);
#else
  return __expf(v * 0.6931471805599453f);
#endif
}
// xor lane-bit-0 exchange via DPP quad_perm [1,0,3,2] (1 VALU op, no LDS)
__device__ __forceinline__ float dpp_xor1(float v) {
  return __builtin_bit_cast(float,
      __builtin_amdgcn_update_dpp(0, __builtin_bit_cast(int, v),
                                  0xB1 /*quad_perm 1,0,3,2*/, 0xF, 0xF, true));
}
// quad_perm [2,3,0,1]: lane 4j gets lane 4j+2's value
__device__ __forceinline__ unsigned int dpp_swap2(unsigned int v) {
  return (unsigned int)__builtin_amdgcn_update_dpp(0, (int)v, 0x4E, 0xF, 0xF, true);
}

// LDS-only workgroup barrier: orders DS ops across waves WITHOUT draining
// vmcnt (global loads/stores stay in flight across steps).
__device__ __forceinline__ void lds_barrier() {
  asm volatile("s_waitcnt lgkmcnt(0)" ::: "memory");
  __builtin_amdgcn_s_barrier();
  __builtin_amdgcn_sched_barrier(0);
}

#define LOG2E  1.4426950408889634f
#define LOG2E2 2.8853900817779268f

// workspace offsets (bytes)
#define O_W1M  0u         // [2][288][96] fp16 = 110592 (lstm1 A, row=u*4+g, K: x8|h70|pad|bias@78, log2e-scaled)
#define O_WP2  110592u    // [2][84][24]  fp16 = 8064   (lstm2 fdot W, row=g*21+u, log2e-scaled)
#define O_W2M  118656u    // [176][168]   fp16 = 59136  (pre2 B, row=out col d*84+u*4+g, log2e-scaled)
#define O_BIAS 177792u    // [176] f32    = 704         (log2e-scaled, unit-major)
#define O_DATA 178496u    // h1/pre2 [rows][176] fp16, then h2 [rows][48] fp16

// ---------------------------------------------------------------------------
// K0: pack all weights.
// ---------------------------------------------------------------------------
__global__ void pack_kernel(const float* __restrict__ wihf, const float* __restrict__ whhf,
                            const float* __restrict__ wihb, const float* __restrict__ whhb,
                            const float* __restrict__ b1if, const float* __restrict__ b1hf,
                            const float* __restrict__ b1ib, const float* __restrict__ b1hb,
                            const float* __restrict__ wih2f, const float* __restrict__ wih2b,
                            const float* __restrict__ whh2f, const float* __restrict__ whh2b,
                            const float* __restrict__ bif, const float* __restrict__ bhf,
                            const float* __restrict__ bib, const float* __restrict__ bhb,
                            char* __restrict__ ws) {
  _Float16* w1m = (_Float16*)(ws + O_W1M);
  _Float16* wp2 = (_Float16*)(ws + O_WP2);
  _Float16* w2m = (_Float16*)(ws + O_W2M);
  float* biasc = (float*)(ws + O_BIAS);
  int idx = blockIdx.x * 256 + threadIdx.x;
  if (idx < 55296) {  // w1m: [d][288 rows (u*4+g)][96 k], log2e-scaled
    int d = idx / 27648, rem = idx % 27648, rp = rem / 96, k = rem % 96;
    int u = rp >> 2, g = rp & 3;
    const float* wih = d ? wihb : wihf;
    const float* whh = d ? whhb : whhf;
    const float* bi = d ? b1ib : b1if;
    const float* bh = d ? b1hb : b1hf;
    float v = 0.f;
    if (u < 70) {
      int src = g * 70 + u;
      float scale = (g == 2) ? LOG2E2 : LOG2E;
      if (k < 8) v = wih[src * 8 + k] * scale;
      else if (k < 78) v = whh[src * 70 + (k - 8)] * scale;
      else if (k == 78) v = (bi[src] + bh[src]) * scale;
    }
    w1m[idx] = (_Float16)v;
  } else if (idx < 59328) {  // wp2: [d][84 rows g*21+u][24 k], log2e-scaled
    int j = idx - 55296;
    int d = j / 2016, rem = j % 2016, r = rem / 24, k = rem % 24;
    const float* whh = d ? whh2b : whh2f;
    float scale = (r / 21 == 2) ? LOG2E2 : LOG2E;
    wp2[j] = (_Float16)((k < 21) ? whh[r * 21 + k] * scale : 0.f);
  } else if (idx < 88896) {  // w2m: [176 out col n=d*84+u*4+g][168 k], scaled
    int j = idx - 59328;  // < 29568
    int n = j / 168, k = j % 168;
    float v = 0.f;
    if (n < 168 && k < 140) {
      int d = n / 84, m = n % 84, u = m >> 2, g = m & 3;
      const float* wih = d ? wih2b : wih2f;
      float scale = (g == 2) ? LOG2E2 : LOG2E;
      v = wih[(g * 21 + u) * 140 + k] * scale;
    }
    w2m[j] = (_Float16)v;
  } else if (idx < 89072) {  // biasc[176], scaled, unit-major order
    int n = idx - 88896;
    float v = 0.f;
    if (n < 168) {
      int d = n / 84, m = n % 84, u = m >> 2, g = m & 3;
      const float* bi = d ? bib : bif;
      const float* bh = d ? bhb : bhf;
      float scale = (g == 2) ? LOG2E2 : LOG2E;
      v = (bi[g * 21 + u] + bh[g * 21 + u]) * scale;
    }
    biasc[n] = v;
  }
}

// ---------------------------------------------------------------------------
// K1: layer-1 LSTM on MFMA. Block = 16 batches x 1 dir, 1024 threads (16
// waves). Tiles: w0,w1 -> 2 (T=2w,2w+1); w2-13 -> 1 (T=w+2); w14 -> 2
// (T=16,17); w15 -> 0 (PURE x-loader wave: its vmem stream is only x
// loads, so the 4-deep x pipeline waits vmcnt(3), never a store drain).
// Per-SIMD (w%4): 5/5/5/3 tiles. A-frag: lane&15 = gate row, lane>>4 =
// k-subchunk. B-frag from LDS km[16][104] (x|h|1.0@78). C/D: lane's 4
// regs = gates i,f,g,o of unit U=T*4+(lane>>4), batch lane&15. Merged-rcp
// GATE (8 trans). One LDS-only barrier/step.
// ---------------------------------------------------------------------------
__global__ __launch_bounds__(1024) void lstm1_kernel(
    const float* __restrict__ x,
    const _Float16* __restrict__ w1m,
    _Float16* __restrict__ h1, int b0, int nb) {
  __shared__ __align__(16) _Float16 km[2][16][104];
  const int tid = threadIdx.x;
  const int w = tid >> 6, lane = tid & 63;
  const int q = lane >> 4, bc = lane & 15;
  const int d = blockIdx.y;
  const int blg = blockIdx.x * 16;   // slice-local batch base
  const int gb0 = b0 + blg;          // global batch base (for x)

  for (int i = tid; i < 2 * 16 * 104; i += 1024) ((_Float16*)km)[i] = (_Float16)0.f;

  const bool ldr = (w == 15);
  const bool two = (w < 2) || (w == 14);
  const int T0 = (w < 2) ? 2 * w : (w == 14 ? 16 : w + 2);

  // A fragments: up to 2 tiles x 3 K-chunks (bias folded at k=78)
  v8h af[2][3];
  if (!ldr) {
#pragma unroll
    for (int kc = 0; kc < 3; ++kc)
      af[0][kc] = *(const v8h*)&w1m[(size_t)(d * 288 + T0 * 16 + bc) * 96 + kc * 32 + q * 8];
    if (two) {
#pragma unroll
      for (int kc = 0; kc < 3; ++kc)
        af[1][kc] = *(const v8h*)&w1m[(size_t)(d * 288 + (T0 + 1) * 16 + bc) * 96 + kc * 32 + q * 8];
    }
  }

  __syncthreads();  // zero-init done before targeted writes below

  if (tid < 16) {  // constant-1.0 column for bias
    km[0][tid][78] = (_Float16)1.f;
    km[1][tid][78] = (_Float16)1.f;
  }
  const bool xlane = ldr && (lane < 32);  // wave 15 lanes 0..31
  const int xb = lane >> 1, xhalf = lane & 1;
  // x for step s lives at t(s) = d ? 1023-s : s
  float4 xa, xb4, xc, xd;            // x for steps s+1..s+4
  const float* xp = nullptr;         // -> t(s+5) element, advanced per step
  const ptrdiff_t xstep = d ? -8 : 8;
  if (xlane) {
    const float* xrow = &x[((size_t)(gb0 + xb) * 1024) * 8 + xhalf * 4];
    int t0 = d ? 1023 : 0;
    float4 xv = *(const float4*)&xrow[(size_t)t0 * 8];
    v4h xh; xh[0] = (_Float16)xv.x; xh[1] = (_Float16)xv.y;
    xh[2] = (_Float16)xv.z; xh[3] = (_Float16)xv.w;
    *(v4h*)&km[0][xb][xhalf * 4] = xh;
    xa  = *(const float4*)&xrow[(size_t)(d ? 1022 : 1) * 8];
    xb4 = *(const float4*)&xrow[(size_t)(d ? 1021 : 2) * 8];
    xc  = *(const float4*)&xrow[(size_t)(d ? 1020 : 3) * 8];
    xd  = *(const float4*)&xrow[(size_t)(d ? 1019 : 4) * 8];
    xp  = &xrow[(size_t)(d ? 1018 : 5) * 8];
  }
  float c0 = 0.f, c1 = 0.f;
  int s = 0;
  __syncthreads();

  // preacts log2e-scaled (g by 2log2e): e = 2^-A. Merged-rcp forms:
  // si*tanh_g = (1-eg)/((1+ei)(1+eg)); so*tanh_c = (1-ec)/((1+eo)(1+ec)),
  // tanh-c exp input clamped so ec stays finite.
#define GATE(Ai, ci, U)                                                      \
    {                                                                        \
      float ei = ex2(-Ai[0]);                                                \
      float ef = ex2(-Ai[1]);                                                \
      float eg = ex2(-Ai[2]);                                                \
      float eo = ex2(-Ai[3]);                                                \
      float sf = rcpf(1.f + ef);                                             \
      float ig = (1.f - eg) * rcpf((1.f + ei) * (1.f + eg));                 \
      ci = fmaf(sf, ci, ig);                                                 \
      float cl = fminf(fmaxf(ci, -14.f), 14.f);                              \
      float ec = ex2(cl * -LOG2E2);                                          \
      float hv = (1.f - ec) * rcpf((1.f + eo) * (1.f + ec));                 \
      if ((U) < 70) {                                                        \
        _Float16 hh = (_Float16)hv;                                          \
        km[nxt][bc][8 + (U)] = hh;                                           \
        h1[rowb + (U)] = hh;                                                 \
      }                                                                      \
    }

#define STEP1(XR)                                                            \
  {                                                                          \
    const int cur = s & 1, nxt = cur ^ 1;                                    \
    if (!ldr) {                                                              \
      v8h bf0 = *(const v8h*)&km[cur][bc][q * 8];                            \
      v8h bf1 = *(const v8h*)&km[cur][bc][32 + q * 8];                       \
      v8h bf2 = *(const v8h*)&km[cur][bc][64 + q * 8];                       \
      f32x4 z4 = (f32x4){0.f, 0.f, 0.f, 0.f};                                \
      f32x4 A0 = __builtin_amdgcn_mfma_f32_16x16x32_f16(af[0][0], bf0, z4, 0, 0, 0); \
      f32x4 A1 = z4;                                                         \
      if (two) A1 = __builtin_amdgcn_mfma_f32_16x16x32_f16(af[1][0], bf0, z4, 0, 0, 0); \
      A0 = __builtin_amdgcn_mfma_f32_16x16x32_f16(af[0][1], bf1, A0, 0, 0, 0); \
      if (two) A1 = __builtin_amdgcn_mfma_f32_16x16x32_f16(af[1][1], bf1, A1, 0, 0, 0); \
      A0 = __builtin_amdgcn_mfma_f32_16x16x32_f16(af[0][2], bf2, A0, 0, 0, 0); \
      if (two) A1 = __builtin_amdgcn_mfma_f32_16x16x32_f16(af[1][2], bf2, A1, 0, 0, 0); \
      const int te = d ? (1023 - s) : s;                                     \
      const size_t rowb = ((size_t)te * nb + blg + bc) * 176 + d * 70;       \
      GATE(A0, c0, T0 * 4 + q)                                               \
      if (two) GATE(A1, c1, (T0 + 1) * 4 + q)                                \
    } else if (xlane) {                                                      \
      if (s < 1023) {                                                        \
        v4h xh; xh[0] = (_Float16)XR.x; xh[1] = (_Float16)XR.y;              \
        xh[2] = (_Float16)XR.z; xh[3] = (_Float16)XR.w;                      \
        *(v4h*)&km[nxt][xb][xhalf * 4] = xh;                                 \
      }                                                                      \
      if (s <= 1018) XR = *(const float4*)xp;                                \
      xp += xstep;                                                           \
    }                                                                        \
    ++s;                                                                     \
    lds_barrier();                                                           \
  }

#pragma unroll 1
  for (int it = 0; it < 256; ++it) {
    STEP1(xa)
    STEP1(xb4)
    STEP1(xc)
    STEP1(xd)
  }
#undef STEP1
#undef GATE
}

// ---------------------------------------------------------------------------
// K2: pre2 MFMA GEMM, in-place over h1. block 256 (4 waves), 64 rows/block.
// C[64][176] = A[64][K=160] * W^T + bias; A staged LDS (stride 184 breaks
// bank conflicts), B frags from global (L2-hot 59KB), next-ct prefetch.
// K 140..159 of the A-fragment zero-masked in-register (h1 pad is garbage).
// Output columns are unit-major (d*84+u*4+g), log2e-scaled.
// ---------------------------------------------------------------------------
__global__ __launch_bounds__(256) void pre2_kernel(
    _Float16* __restrict__ h1, const char* __restrict__ ws) {
  const _Float16* w2m = (const _Float16*)(ws + O_W2M);
  const float* biasc = (const float*)(ws + O_BIAS);
  __shared__ _Float16 Al[64][184];
  __shared__ float Bl[176];
  const int tid = threadIdx.x;
  const int r0 = blockIdx.x * 64;
  // stage A (64 rows x 176 cols = 1408 v8h)
#pragma unroll
  for (int i = 0; i < 6; ++i) {
    int cid = i * 256 + tid;
    if (cid < 1408) {
      int row = cid / 22, ch = cid % 22;
      *(v8h*)&Al[row][ch * 8] = *(const v8h*)&h1[(size_t)(r0 + row) * 176 + ch * 8];
    }
  }
  if (tid < 176) Bl[tid] = biasc[tid];
  __syncthreads();

  const int wv = tid >> 6, lane = tid & 63;
  const int ml = lane & 15, kq = lane >> 4;
  // A fragments (5 K-chunks of 32); chunk 4 masked: cols 140..159 -> 0
  v8h af[5];
#pragma unroll
  for (int k = 0; k < 4; ++k)
    af[k] = *(const v8h*)&Al[wv * 16 + ml][k * 32 + kq * 8];
  {
    v8h a4 = *(const v8h*)&Al[wv * 16 + ml][128 + kq * 8];
    if (kq >= 2) {
#pragma unroll
      for (int j = 0; j < 8; ++j) a4[j] = (_Float16)0.f;
    } else if (kq == 1) {
#pragma unroll
      for (int j = 4; j < 8; ++j) a4[j] = (_Float16)0.f;
    }
    af[4] = a4;
  }

  const v8h* wg = (const v8h*)w2m;  // row stride 21 v8h
  f32x4 acc[11];
#pragma unroll
  for (int ct = 0; ct < 11; ++ct) acc[ct] = (f32x4){0.f, 0.f, 0.f, 0.f};

  v8h bc[5], bn[5];
#pragma unroll
  for (int k = 0; k < 5; ++k) bn[k] = wg[(size_t)ml * 21 + k * 4 + kq];
#pragma unroll
  for (int ct = 0; ct < 11; ++ct) {
#pragma unroll
    for (int k = 0; k < 5; ++k) bc[k] = bn[k];
    if (ct < 10) {
#pragma unroll
      for (int k = 0; k < 5; ++k) bn[k] = wg[(size_t)((ct + 1) * 16 + ml) * 21 + k * 4 + kq];
    }
#pragma unroll
    for (int k = 0; k < 5; ++k)
      acc[ct] = __builtin_amdgcn_mfma_f32_16x16x32_f16(af[k], bc[k], acc[ct], 0, 0, 0);
  }
  __syncthreads();  // all waves done with Al frags
  // C -> Al (fp16, +bias), then coalesced flat store over h1
#pragma unroll
  for (int ct = 0; ct < 11; ++ct) {
#pragma unroll
    for (int r = 0; r < 4; ++r) {
      int row = wv * 16 + kq * 4 + r, col = ct * 16 + ml;
      Al[row][col] = (_Float16)(acc[ct][r] + Bl[col]);
    }
  }
  __syncthreads();
#pragma unroll
  for (int i = 0; i < 6; ++i) {
    int cid = i * 256 + tid;
    if (cid < 1408) {
      int row = cid / 22, ch = cid % 22;
      *(v8h*)&h1[(size_t)(r0 + row) * 176 + ch * 8] = *(const v8h*)&Al[row][ch * 8];
    }
  }
}

// ---------------------------------------------------------------------------
// K3: layer-2 LSTM, ONE 64-lane wave per (batch, dir). lane = u*2+p, u<21:
// lane computes gate rows {2p, 2p+1} (11 fdot2 each, 4-way split chains);
// quad completed by ONE DPP quad_perm exchange. ZERO LDS: wave-uniform h
// vector kept in 11 dwords, refreshed per step via cvt + quad_perm[2,3,0,1]
// pack + 11 readlanes (both lanes of a unit pair compute identical hv).
// Pair-10 high half from lane40's zero-extended value. pre2 preacts
// unit-major, one v2f16 load, 8-deep prefetch. setprio(1) around dot+act.
// ---------------------------------------------------------------------------
__global__ __launch_bounds__(64) void lstm2_kernel(
    const _Float16* __restrict__ pre2, const _Float16* __restrict__ wp2,
    _Float16* __restrict__ h2, int nb) {
  const int lane = threadIdx.x;
  const int bl = blockIdx.x;
  const int d = blockIdx.y;
  const int u = lane >> 1, p = lane & 1;
  const bool active = lane < 42;

  v2f16 w0[12], w1[12];
  if (active) {
    const v8h* wr0 = (const v8h*)&wp2[(d * 84 + (2 * p) * 21 + u) * 24];
    const v8h* wr1 = (const v8h*)&wp2[(d * 84 + (2 * p + 1) * 21 + u) * 24];
#pragma unroll
    for (int ch = 0; ch < 3; ++ch) {
      v8h a = wr0[ch], b = wr1[ch];
#pragma unroll
      for (int q = 0; q < 4; ++q) {
        v2f16 t0; t0[0] = a[2 * q]; t0[1] = a[2 * q + 1]; w0[ch * 4 + q] = t0;
        v2f16 t1; t1[0] = b[2 * q]; t1[1] = b[2 * q + 1]; w1[ch * 4 + q] = t1;
      }
    }
  }
  // unit-major pre2: gates (2p, 2p+1) of unit u are ADJACENT columns
  const int cp = d * 84 + u * 4 + 2 * p;
  const ptrdiff_t dlt = (ptrdiff_t)(d ? -nb : nb) * 176;
  const _Float16* pp = pre2 + ((size_t)(d ? 1023 : 0) * (size_t)nb + bl) * 176;

  // 8-deep prefetch pipeline: one v2f16 per step
  v2f16 pa = *(const v2f16*)(pp + cp);
  v2f16 pb = *(const v2f16*)(pp + dlt + cp);
  v2f16 pc = *(const v2f16*)(pp + 2 * dlt + cp);
  v2f16 pd = *(const v2f16*)(pp + 3 * dlt + cp);
  v2f16 pe = *(const v2f16*)(pp + 4 * dlt + cp);
  v2f16 pg = *(const v2f16*)(pp + 5 * dlt + cp);
  v2f16 ph = *(const v2f16*)(pp + 6 * dlt + cp);
  v2f16 pi = *(const v2f16*)(pp + 7 * dlt + cp);
  const _Float16* pf = pp + 8 * dlt;

  // wave-uniform h vector: sk[j] = (h[2j], h[2j+1]); h(0) = 0
  v2f16 sk[11];
#pragma unroll
  for (int j = 0; j < 11; ++j) {
    v2f16 z; z[0] = (_Float16)0.f; z[1] = (_Float16)0.f; sk[j] = z;
  }

  float cc = 0.f;
  int s = 0;

#define L2STEP(P)                                                           \
  {                                                                         \
    float A0v = (float)P[0], A1v = (float)P[1];                             \
    __builtin_amdgcn_s_setprio(1);                                          \
    float x0 = A0v, x1 = 0.f, x2 = 0.f, x3 = 0.f;                           \
    float z0 = A1v, z1 = 0.f, z2 = 0.f, z3 = 0.f;                           \
    x0 = fdot2(sk[0], w0[0], x0);                                           \
    x1 = fdot2(sk[1], w0[1], x1);                                           \
    x2 = fdot2(sk[2], w0[2], x2);                                           \
    x3 = fdot2(sk[3], w0[3], x3);                                           \
    x0 = fdot2(sk[4], w0[4], x0);                                           \
    x1 = fdot2(sk[5], w0[5], x1);                                           \
    x2 = fdot2(sk[6], w0[6], x2);                                           \
    x3 = fdot2(sk[7], w0[7], x3);                                           \
    x0 = fdot2(sk[8], w0[8], x0);                                           \
    x1 = fdot2(sk[9], w0[9], x1);                                           \
    x2 = fdot2(sk[10], w0[10], x2);                                         \
    z0 = fdot2(sk[0], w1[0], z0);                                           \
    z1 = fdot2(sk[1], w1[1], z1);                                           \
    z2 = fdot2(sk[2], w1[2], z2);                                           \
    z3 = fdot2(sk[3], w1[3], z3);                                           \
    z0 = fdot2(sk[4], w1[4], z0);                                           \
    z1 = fdot2(sk[5], w1[5], z1);                                           \
    z2 = fdot2(sk[6], w1[6], z2);                                           \
    z3 = fdot2(sk[7], w1[7], z3);                                           \
    z0 = fdot2(sk[8], w1[8], z0);                                           \
    z1 = fdot2(sk[9], w1[9], z1);                                           \
    z2 = fdot2(sk[10], w1[10], z2);                                         \
    float A = (x0 + x1) + (x2 + x3), Bv = (z0 + z1) + (z2 + z3);            \
    /* row0 = gate 2p (p=0: i sigm, p=1: g tanh); row1 = f/o sigm */        \
    float r0v = rcpf(1.f + ex2(-A));                                        \
    float Y0 = p ? fmaf(2.f, r0v, -1.f) : r0v;                              \
    float Y1 = rcpf(1.f + ex2(-Bv));                                        \
    float Zs = dpp_xor1(Y0);                                                \
    float Ws = dpp_xor1(Y1);                                                \
    float ai = p ? Zs : Y0;                                                 \
    float af = p ? Ws : Y1;                                                 \
    float ag = p ? Y0 : Zs;                                                 \
    float ao = p ? Y1 : Ws;                                                 \
    cc = fmaf(af, cc, ai * ag);                                             \
    float tc = fmaf(2.f, rcpf(1.f + ex2(cc * -LOG2E2)), -1.f);              \
    float hv = ao * tc;                                                     \
    _Float16 hh = (_Float16)hv;                                             \
    /* broadcast h: lane 4j packs (h[2j],h[2j+1]); readlane -> uniform */   \
    unsigned int hvh = (unsigned int)__builtin_bit_cast(unsigned short, hh);\
    unsigned int on = dpp_swap2(hvh);                                       \
    unsigned int pk = hvh | (on << 16);                                     \
    sk[0]  = __builtin_bit_cast(v2f16, __builtin_amdgcn_readlane((int)pk, 0));   \
    sk[1]  = __builtin_bit_cast(v2f16, __builtin_amdgcn_readlane((int)pk, 4));   \
    sk[2]  = __builtin_bit_cast(v2f16, __builtin_amdgcn_readlane((int)pk, 8));   \
    sk[3]  = __builtin_bit_cast(v2f16, __builtin_amdgcn_readlane((int)pk, 12));  \
    sk[4]  = __builtin_bit_cast(v2f16, __builtin_amdgcn_readlane((int)pk, 16));  \
    sk[5]  = __builtin_bit_cast(v2f16, __builtin_amdgcn_readlane((int)pk, 20));  \
    sk[6]  = __builtin_bit_cast(v2f16, __builtin_amdgcn_readlane((int)pk, 24));  \
    sk[7]  = __builtin_bit_cast(v2f16, __builtin_amdgcn_readlane((int)pk, 28));  \
    sk[8]  = __builtin_bit_cast(v2f16, __builtin_amdgcn_readlane((int)pk, 32));  \
    sk[9]  = __builtin_bit_cast(v2f16, __builtin_amdgcn_readlane((int)pk, 36));  \
    sk[10] = __builtin_bit_cast(v2f16, __builtin_amdgcn_readlane((int)hvh, 40)); \
    __builtin_amdgcn_s_setprio(0);                                          \
    if (active && p == 0) {                                                 \
      int te = d ? (1023 - s) : s;                                          \
      h2[((size_t)te * nb + bl) * 48 + d * 21 + u] = hh;                    \
    }                                                                       \
    if (s < 1016) P = *(const v2f16*)(pf + cp);                             \
    pf += dlt;                                                              \
    ++s;                                                                    \
  }

#pragma unroll 1
  for (int it = 0; it < 128; ++it) {
    L2STEP(pa)
    L2STEP(pb)
    L2STEP(pc)
    L2STEP(pd)
    L2STEP(pe)
    L2STEP(pg)
    L2STEP(ph)
    L2STEP(pi)
  }
#undef L2STEP
}

// ---------------------------------------------------------------------------
// K4: dense head. local row = t*nb+bl -> out[(b0+bl)*1024 + t].
// ---------------------------------------------------------------------------
__global__ __launch_bounds__(256) void head_kernel(
    const _Float16* __restrict__ h2,
    const float* __restrict__ d1w, const float* __restrict__ d1b,
    const float* __restrict__ d2w, const float* __restrict__ d2b,
    const float* __restrict__ ow, const float* __restrict__ ob,
    float* __restrict__ out, int b0, int lognb) {
  int n = blockIdx.x * 256 + threadIdx.x;
  int t = n >> lognb, bl = n & ((1 << lognb) - 1);
  const v8h* hp = (const v8h*)&h2[(size_t)n * 48];
  float in[48];
#pragma unroll
  for (int i = 0; i < 6; ++i) {
    v8h hc = hp[i];
#pragma unroll
    for (int j = 0; j < 8; ++j) in[i * 8 + j] = (float)hc[j];
  }
  float a1[30];
#pragma unroll
  for (int cc = 0; cc < 30; ++cc) {
    float a = d1b[cc];
#pragma unroll
    for (int k = 0; k < 42; ++k) a += in[k] * d1w[cc * 42 + k];
    a1[cc] = fmaxf(a, 0.f);
  }
  float a2[20];
#pragma unroll
  for (int cc = 0; cc < 20; ++cc) {
    float a = d2b[cc];
#pragma unroll
    for (int k = 0; k < 30; ++k) a += a1[k] * d2w[cc * 30 + k];
    a2[cc] = fmaxf(a, 0.f);
  }
  float o = ob[0];
#pragma unroll
  for (int k = 0; k < 20; ++k) o += a2[k] * ow[k];
  out[(size_t)(b0 + bl) * 1024 + t] = o;
}

// ---------------------------------------------------------------------------
extern "C" void kernel_launch(void* const* d_in, const int* in_sizes, int n_in,
                              void* d_out, int out_size, void* d_ws, size_t ws_size,
                              hipStream_t stream) {
  const float* x = (const float*)d_in[0];
  const float* wih1f = (const float*)d_in[1];
  const float* whh1f = (const float*)d_in[2];
  const float* bih1f = (const float*)d_in[3];
  const float* bhh1f = (const float*)d_in[4];
  const float* wih1b = (const float*)d_in[5];
  const float* whh1b = (const float*)d_in[6];
  const float* bih1b = (const float*)d_in[7];
  const float* bhh1b = (const float*)d_in[8];
  const float* wih2f = (const float*)d_in[9];
  const float* whh2f = (const float*)d_in[10];
  const float* bih2f = (const float*)d_in[11];
  const float* bhh2f = (const float*)d_in[12];
  const float* wih2b = (const float*)d_in[13];
  const float* whh2b = (const float*)d_in[14];
  const float* bih2b = (const float*)d_in[15];
  const float* bhh2b = (const float*)d_in[16];
  const float* d1w = (const float*)d_in[17];
  const float* d1b = (const float*)d_in[18];
  const float* d2w = (const float*)d_in[19];
  const float* d2b = (const float*)d_in[20];
  const float* ow = (const float*)d_in[21];
  const float* ob = (const float*)d_in[22];
  float* out = (float*)d_out;
  char* wsb = (char*)d_ws;

  // adaptive batch slicing: per-slice bytes = rows*(352 + 96), rows = nb*1024
  const int cands[6] = {1, 2, 4, 8, 16, 32};
  int nslice = 32;
  for (int i = 0; i < 6; ++i) {
    size_t rows = (size_t)(512 / cands[i]) * 1024;
    if (O_DATA + rows * 448 <= ws_size) { nslice = cands[i]; break; }
  }
  const int nb = 512 / nslice;
  int lognb = 0; while ((1 << lognb) < nb) ++lognb;
  const size_t rows = (size_t)nb * 1024;

  _Float16* w1m = (_Float16*)(wsb + O_W1M);
  _Float16* wp2 = (_Float16*)(wsb + O_WP2);
  _Float16* h1  = (_Float16*)(wsb + O_DATA);          // becomes pre2 in place
  _Float16* h2  = (_Float16*)(wsb + O_DATA + rows * 352);

  pack_kernel<<<348, 256, 0, stream>>>(wih1f, whh1f, wih1b, whh1b,
                                       bih1f, bhh1f, bih1b, bhh1b,
                                       wih2f, wih2b, whh2f, whh2b,
                                       bih2f, bhh2f, bih2b, bhh2b, wsb);

  for (int s = 0; s < nslice; ++s) {
    const int b0 = s * nb;
    lstm1_kernel<<<dim3(nb / 16, 2), 1024, 0, stream>>>(x, w1m, h1, b0, nb);
    pre2_kernel<<<nb * 16, 256, 0, stream>>>(h1, wsb);
    lstm2_kernel<<<dim3(nb, 2), 64, 0, stream>>>(h1, wp2, h2, nb);
    head_kernel<<<nb * 4, 256, 0, stream>>>(h2, d1w, d1b, d2w, d2b, ow, ob,
                                            out, b0, lognb);
  }
}

// Round 16
// 1196.524 us; speedup vs baseline: 1.4914x; 1.0338x over previous
//
#include <hip/hip_runtime.h>

// ---------------------------------------------------------------------------
// BiLSTM(70) -> BiLSTM(21) -> MLP head. B=512 T=1024 F=8.
//
// R18: restore R14 verbatim (best verified: 1201us). R17's register-
//      broadcast h-exchange regressed (+36us: 11 serial readlanes sit ahead
//      of ALL next-step fdot2s, vs the LDS kv read whose latency was
//      already hidden by the double-buffer) -> lstm2's R14 form is its
//      local optimum. Search ledger: lstm1 wave-count saturated, trans
//      cuts null x2, x-loader-wave fix banked (-76us), LDS layout 2-way-
//      free; lstm2 topology proven (1024x1-wave beats both packings),
//      8-deep prefetch, DPP quad_perm exchange, setprio(+11us); pre2
//      fusion disproven (atomic RMW 4x traffic). Remaining time is the
//      serial-recurrence latency floor (1024 barriers x ~1400cy chained
//      LDS->MFMA->trans->LDS), not a counter-visible roofline.
// ---------------------------------------------------------------------------

typedef _Float16 v2f16 __attribute__((ext_vector_type(2)));
typedef _Float16 v4h   __attribute__((ext_vector_type(4)));
typedef _Float16 v8h   __attribute__((ext_vector_type(8)));
typedef float    f32x4 __attribute__((ext_vector_type(4)));

__device__ __forceinline__ float fdot2(v2f16 a, v2f16 b, float c) {
  return __builtin_amdgcn_fdot2(a, b, c, false);
}
#if __has_builtin(__builtin_amdgcn_rcpf)
__device__ __forceinline__ float rcpf(float x) { return __builtin_amdgcn_rcpf(x); }
#else
__device__ __forceinline__ float rcpf(float x) { return 1.f / x; }
#endif
// raw 2^x (weights pre-scaled by log2e so activations need no mul)
__device__ __forceinline__ float ex2(float v) {
#if __has_builtin(__builtin_amdgcn_exp2f)
  return __builtin_amdgcn_exp2f(v);
#else
  return __expf(v * 0.6931471805599453f);
#endif
}
// xor lane-bit-0 exchange via DPP quad_perm [1,0,3,2] (1 VALU op, no LDS)
__device__ __forceinline__ float dpp_xor1(float v) {
  return __builtin_bit_cast(float,
      __builtin_amdgcn_update_dpp(0, __builtin_bit_cast(int, v),
                                  0xB1 /*quad_perm 1,0,3,2*/, 0xF, 0xF, true));
}

// LDS-only workgroup barrier: orders DS ops across waves WITHOUT draining
// vmcnt (global loads/stores stay in flight across steps).
__device__ __forceinline__ void lds_barrier() {
  asm volatile("s_waitcnt lgkmcnt(0)" ::: "memory");
  __builtin_amdgcn_s_barrier();
  __builtin_amdgcn_sched_barrier(0);
}

#define LOG2E  1.4426950408889634f
#define LOG2E2 2.8853900817779268f

// workspace offsets (bytes)
#define O_W1M  0u         // [2][288][96] fp16 = 110592 (lstm1 A, row=u*4+g, K: x8|h70|pad|bias@78, log2e-scaled)
#define O_WP2  110592u    // [2][84][24]  fp16 = 8064   (lstm2 fdot W, row=g*21+u, log2e-scaled)
#define O_W2M  118656u    // [176][168]   fp16 = 59136  (pre2 B, row=out col d*84+u*4+g, log2e-scaled)
#define O_BIAS 177792u    // [176] f32    = 704         (log2e-scaled, unit-major)
#define O_DATA 178496u    // h1/pre2 [rows][176] fp16, then h2 [rows][48] fp16

// ---------------------------------------------------------------------------
// K0: pack all weights.
// ---------------------------------------------------------------------------
__global__ void pack_kernel(const float* __restrict__ wihf, const float* __restrict__ whhf,
                            const float* __restrict__ wihb, const float* __restrict__ whhb,
                            const float* __restrict__ b1if, const float* __restrict__ b1hf,
                            const float* __restrict__ b1ib, const float* __restrict__ b1hb,
                            const float* __restrict__ wih2f, const float* __restrict__ wih2b,
                            const float* __restrict__ whh2f, const float* __restrict__ whh2b,
                            const float* __restrict__ bif, const float* __restrict__ bhf,
                            const float* __restrict__ bib, const float* __restrict__ bhb,
                            char* __restrict__ ws) {
  _Float16* w1m = (_Float16*)(ws + O_W1M);
  _Float16* wp2 = (_Float16*)(ws + O_WP2);
  _Float16* w2m = (_Float16*)(ws + O_W2M);
  float* biasc = (float*)(ws + O_BIAS);
  int idx = blockIdx.x * 256 + threadIdx.x;
  if (idx < 55296) {  // w1m: [d][288 rows (u*4+g)][96 k], log2e-scaled
    int d = idx / 27648, rem = idx % 27648, rp = rem / 96, k = rem % 96;
    int u = rp >> 2, g = rp & 3;
    const float* wih = d ? wihb : wihf;
    const float* whh = d ? whhb : whhf;
    const float* bi = d ? b1ib : b1if;
    const float* bh = d ? b1hb : b1hf;
    float v = 0.f;
    if (u < 70) {
      int src = g * 70 + u;
      float scale = (g == 2) ? LOG2E2 : LOG2E;
      if (k < 8) v = wih[src * 8 + k] * scale;
      else if (k < 78) v = whh[src * 70 + (k - 8)] * scale;
      else if (k == 78) v = (bi[src] + bh[src]) * scale;
    }
    w1m[idx] = (_Float16)v;
  } else if (idx < 59328) {  // wp2: [d][84 rows g*21+u][24 k], log2e-scaled
    int j = idx - 55296;
    int d = j / 2016, rem = j % 2016, r = rem / 24, k = rem % 24;
    const float* whh = d ? whh2b : whh2f;
    float scale = (r / 21 == 2) ? LOG2E2 : LOG2E;
    wp2[j] = (_Float16)((k < 21) ? whh[r * 21 + k] * scale : 0.f);
  } else if (idx < 88896) {  // w2m: [176 out col n=d*84+u*4+g][168 k], scaled
    int j = idx - 59328;  // < 29568
    int n = j / 168, k = j % 168;
    float v = 0.f;
    if (n < 168 && k < 140) {
      int d = n / 84, m = n % 84, u = m >> 2, g = m & 3;
      const float* wih = d ? wih2b : wih2f;
      float scale = (g == 2) ? LOG2E2 : LOG2E;
      v = wih[(g * 21 + u) * 140 + k] * scale;
    }
    w2m[j] = (_Float16)v;
  } else if (idx < 89072) {  // biasc[176], scaled, unit-major order
    int n = idx - 88896;
    float v = 0.f;
    if (n < 168) {
      int d = n / 84, m = n % 84, u = m >> 2, g = m & 3;
      const float* bi = d ? bib : bif;
      const float* bh = d ? bhb : bhf;
      float scale = (g == 2) ? LOG2E2 : LOG2E;
      v = (bi[g * 21 + u] + bh[g * 21 + u]) * scale;
    }
    biasc[n] = v;
  }
}

// ---------------------------------------------------------------------------
// K1: layer-1 LSTM on MFMA. Block = 16 batches x 1 dir, 1024 threads (16
// waves). Tiles: w0,w1 -> 2 (T=2w,2w+1); w2-13 -> 1 (T=w+2); w14 -> 2
// (T=16,17); w15 -> 0 (PURE x-loader wave: its vmem stream is only x
// loads, so the 4-deep x pipeline waits vmcnt(3), never a store drain).
// Per-SIMD (w%4): 5/5/5/3 tiles. A-frag: lane&15 = gate row, lane>>4 =
// k-subchunk. B-frag from LDS km[16][104] (x|h|1.0@78). C/D: lane's 4
// regs = gates i,f,g,o of unit U=T*4+(lane>>4), batch lane&15. Merged-rcp
// GATE (8 trans). One LDS-only barrier/step.
// ---------------------------------------------------------------------------
__global__ __launch_bounds__(1024) void lstm1_kernel(
    const float* __restrict__ x,
    const _Float16* __restrict__ w1m,
    _Float16* __restrict__ h1, int b0, int nb) {
  __shared__ __align__(16) _Float16 km[2][16][104];
  const int tid = threadIdx.x;
  const int w = tid >> 6, lane = tid & 63;
  const int q = lane >> 4, bc = lane & 15;
  const int d = blockIdx.y;
  const int blg = blockIdx.x * 16;   // slice-local batch base
  const int gb0 = b0 + blg;          // global batch base (for x)

  for (int i = tid; i < 2 * 16 * 104; i += 1024) ((_Float16*)km)[i] = (_Float16)0.f;

  const bool ldr = (w == 15);
  const bool two = (w < 2) || (w == 14);
  const int T0 = (w < 2) ? 2 * w : (w == 14 ? 16 : w + 2);

  // A fragments: up to 2 tiles x 3 K-chunks (bias folded at k=78)
  v8h af[2][3];
  if (!ldr) {
#pragma unroll
    for (int kc = 0; kc < 3; ++kc)
      af[0][kc] = *(const v8h*)&w1m[(size_t)(d * 288 + T0 * 16 + bc) * 96 + kc * 32 + q * 8];
    if (two) {
#pragma unroll
      for (int kc = 0; kc < 3; ++kc)
        af[1][kc] = *(const v8h*)&w1m[(size_t)(d * 288 + (T0 + 1) * 16 + bc) * 96 + kc * 32 + q * 8];
    }
  }

  __syncthreads();  // zero-init done before targeted writes below

  if (tid < 16) {  // constant-1.0 column for bias
    km[0][tid][78] = (_Float16)1.f;
    km[1][tid][78] = (_Float16)1.f;
  }
  const bool xlane = ldr && (lane < 32);  // wave 15 lanes 0..31
  const int xb = lane >> 1, xhalf = lane & 1;
  // x for step s lives at t(s) = d ? 1023-s : s
  float4 xa, xb4, xc, xd;            // x for steps s+1..s+4
  const float* xp = nullptr;         // -> t(s+5) element, advanced per step
  const ptrdiff_t xstep = d ? -8 : 8;
  if (xlane) {
    const float* xrow = &x[((size_t)(gb0 + xb) * 1024) * 8 + xhalf * 4];
    int t0 = d ? 1023 : 0;
    float4 xv = *(const float4*)&xrow[(size_t)t0 * 8];
    v4h xh; xh[0] = (_Float16)xv.x; xh[1] = (_Float16)xv.y;
    xh[2] = (_Float16)xv.z; xh[3] = (_Float16)xv.w;
    *(v4h*)&km[0][xb][xhalf * 4] = xh;
    xa  = *(const float4*)&xrow[(size_t)(d ? 1022 : 1) * 8];
    xb4 = *(const float4*)&xrow[(size_t)(d ? 1021 : 2) * 8];
    xc  = *(const float4*)&xrow[(size_t)(d ? 1020 : 3) * 8];
    xd  = *(const float4*)&xrow[(size_t)(d ? 1019 : 4) * 8];
    xp  = &xrow[(size_t)(d ? 1018 : 5) * 8];
  }
  float c0 = 0.f, c1 = 0.f;
  int s = 0;
  __syncthreads();

  // preacts log2e-scaled (g by 2log2e): e = 2^-A. Merged-rcp forms:
  // si*tanh_g = (1-eg)/((1+ei)(1+eg)); so*tanh_c = (1-ec)/((1+eo)(1+ec)),
  // tanh-c exp input clamped so ec stays finite.
#define GATE(Ai, ci, U)                                                      \
    {                                                                        \
      float ei = ex2(-Ai[0]);                                                \
      float ef = ex2(-Ai[1]);                                                \
      float eg = ex2(-Ai[2]);                                                \
      float eo = ex2(-Ai[3]);                                                \
      float sf = rcpf(1.f + ef);                                             \
      float ig = (1.f - eg) * rcpf((1.f + ei) * (1.f + eg));                 \
      ci = fmaf(sf, ci, ig);                                                 \
      float cl = fminf(fmaxf(ci, -14.f), 14.f);                              \
      float ec = ex2(cl * -LOG2E2);                                          \
      float hv = (1.f - ec) * rcpf((1.f + eo) * (1.f + ec));                 \
      if ((U) < 70) {                                                        \
        _Float16 hh = (_Float16)hv;                                          \
        km[nxt][bc][8 + (U)] = hh;                                           \
        h1[rowb + (U)] = hh;                                                 \
      }                                                                      \
    }

#define STEP1(XR)                                                            \
  {                                                                          \
    const int cur = s & 1, nxt = cur ^ 1;                                    \
    if (!ldr) {                                                              \
      v8h bf0 = *(const v8h*)&km[cur][bc][q * 8];                            \
      v8h bf1 = *(const v8h*)&km[cur][bc][32 + q * 8];                       \
      v8h bf2 = *(const v8h*)&km[cur][bc][64 + q * 8];                       \
      f32x4 z4 = (f32x4){0.f, 0.f, 0.f, 0.f};                                \
      f32x4 A0 = __builtin_amdgcn_mfma_f32_16x16x32_f16(af[0][0], bf0, z4, 0, 0, 0); \
      f32x4 A1 = z4;                                                         \
      if (two) A1 = __builtin_amdgcn_mfma_f32_16x16x32_f16(af[1][0], bf0, z4, 0, 0, 0); \
      A0 = __builtin_amdgcn_mfma_f32_16x16x32_f16(af[0][1], bf1, A0, 0, 0, 0); \
      if (two) A1 = __builtin_amdgcn_mfma_f32_16x16x32_f16(af[1][1], bf1, A1, 0, 0, 0); \
      A0 = __builtin_amdgcn_mfma_f32_16x16x32_f16(af[0][2], bf2, A0, 0, 0, 0); \
      if (two) A1 = __builtin_amdgcn_mfma_f32_16x16x32_f16(af[1][2], bf2, A1, 0, 0, 0); \
      const int te = d ? (1023 - s) : s;                                     \
      const size_t rowb = ((size_t)te * nb + blg + bc) * 176 + d * 70;       \
      GATE(A0, c0, T0 * 4 + q)                                               \
      if (two) GATE(A1, c1, (T0 + 1) * 4 + q)                                \
    } else if (xlane) {                                                      \
      if (s < 1023) {                                                        \
        v4h xh; xh[0] = (_Float16)XR.x; xh[1] = (_Float16)XR.y;              \
        xh[2] = (_Float16)XR.z; xh[3] = (_Float16)XR.w;                      \
        *(v4h*)&km[nxt][xb][xhalf * 4] = xh;                                 \
      }                                                                      \
      if (s <= 1018) XR = *(const float4*)xp;                                \
      xp += xstep;                                                           \
    }                                                                        \
    ++s;                                                                     \
    lds_barrier();                                                           \
  }

#pragma unroll 1
  for (int it = 0; it < 256; ++it) {
    STEP1(xa)
    STEP1(xb4)
    STEP1(xc)
    STEP1(xd)
  }
#undef STEP1
#undef GATE
}

// ---------------------------------------------------------------------------
// K2: pre2 MFMA GEMM, in-place over h1. block 256 (4 waves), 64 rows/block.
// C[64][176] = A[64][K=160] * W^T + bias; A staged LDS (stride 184 breaks
// bank conflicts), B frags from global (L2-hot 59KB), next-ct prefetch.
// K 140..159 of the A-fragment zero-masked in-register (h1 pad is garbage).
// Output columns are unit-major (d*84+u*4+g), log2e-scaled.
// ---------------------------------------------------------------------------
__global__ __launch_bounds__(256) void pre2_kernel(
    _Float16* __restrict__ h1, const char* __restrict__ ws) {
  const _Float16* w2m = (const _Float16*)(ws + O_W2M);
  const float* biasc = (const float*)(ws + O_BIAS);
  __shared__ _Float16 Al[64][184];
  __shared__ float Bl[176];
  const int tid = threadIdx.x;
  const int r0 = blockIdx.x * 64;
  // stage A (64 rows x 176 cols = 1408 v8h)
#pragma unroll
  for (int i = 0; i < 6; ++i) {
    int cid = i * 256 + tid;
    if (cid < 1408) {
      int row = cid / 22, ch = cid % 22;
      *(v8h*)&Al[row][ch * 8] = *(const v8h*)&h1[(size_t)(r0 + row) * 176 + ch * 8];
    }
  }
  if (tid < 176) Bl[tid] = biasc[tid];
  __syncthreads();

  const int wv = tid >> 6, lane = tid & 63;
  const int ml = lane & 15, kq = lane >> 4;
  // A fragments (5 K-chunks of 32); chunk 4 masked: cols 140..159 -> 0
  v8h af[5];
#pragma unroll
  for (int k = 0; k < 4; ++k)
    af[k] = *(const v8h*)&Al[wv * 16 + ml][k * 32 + kq * 8];
  {
    v8h a4 = *(const v8h*)&Al[wv * 16 + ml][128 + kq * 8];
    if (kq >= 2) {
#pragma unroll
      for (int j = 0; j < 8; ++j) a4[j] = (_Float16)0.f;
    } else if (kq == 1) {
#pragma unroll
      for (int j = 4; j < 8; ++j) a4[j] = (_Float16)0.f;
    }
    af[4] = a4;
  }

  const v8h* wg = (const v8h*)w2m;  // row stride 21 v8h
  f32x4 acc[11];
#pragma unroll
  for (int ct = 0; ct < 11; ++ct) acc[ct] = (f32x4){0.f, 0.f, 0.f, 0.f};

  v8h bc[5], bn[5];
#pragma unroll
  for (int k = 0; k < 5; ++k) bn[k] = wg[(size_t)ml * 21 + k * 4 + kq];
#pragma unroll
  for (int ct = 0; ct < 11; ++ct) {
#pragma unroll
    for (int k = 0; k < 5; ++k) bc[k] = bn[k];
    if (ct < 10) {
#pragma unroll
      for (int k = 0; k < 5; ++k) bn[k] = wg[(size_t)((ct + 1) * 16 + ml) * 21 + k * 4 + kq];
    }
#pragma unroll
    for (int k = 0; k < 5; ++k)
      acc[ct] = __builtin_amdgcn_mfma_f32_16x16x32_f16(af[k], bc[k], acc[ct], 0, 0, 0);
  }
  __syncthreads();  // all waves done with Al frags
  // C -> Al (fp16, +bias), then coalesced flat store over h1
#pragma unroll
  for (int ct = 0; ct < 11; ++ct) {
#pragma unroll
    for (int r = 0; r < 4; ++r) {
      int row = wv * 16 + kq * 4 + r, col = ct * 16 + ml;
      Al[row][col] = (_Float16)(acc[ct][r] + Bl[col]);
    }
  }
  __syncthreads();
#pragma unroll
  for (int i = 0; i < 6; ++i) {
    int cid = i * 256 + tid;
    if (cid < 1408) {
      int row = cid / 22, ch = cid % 22;
      *(v8h*)&h1[(size_t)(r0 + row) * 176 + ch * 8] = *(const v8h*)&Al[row][ch * 8];
    }
  }
}

// ---------------------------------------------------------------------------
// K3: layer-2 LSTM, ONE 64-lane wave per (batch, dir). lane = u*2+p, u<21:
// lane computes gate rows {2p, 2p+1} (12 fdot2 each, 4-way split chains);
// quad completed by ONE DPP quad_perm exchange. NO barriers (single wave).
// pre2 preacts: unit-major -> lane's gate pair is one v2f16 load,
// prefetched EIGHT steps deep. s_setprio(1) around the dot+act region.
// Weights/preacts log2e-scaled -> raw exp2. h2 row = t*nb+bl, stride 48.
// ---------------------------------------------------------------------------
__global__ __launch_bounds__(64) void lstm2_kernel(
    const _Float16* __restrict__ pre2, const _Float16* __restrict__ wp2,
    _Float16* __restrict__ h2, int nb) {
  __shared__ __align__(16) _Float16 kv[2][32];  // [buf][ 0..20 h | 21..31 zero ]
  const int lane = threadIdx.x;
  const int bl = blockIdx.x;
  const int d = blockIdx.y;
  const int u = lane >> 1, p = lane & 1;
  const bool active = lane < 42;

  ((_Float16*)kv)[lane] = (_Float16)0.f;  // 64 entries, 64 lanes

  v2f16 w0[12], w1[12];
  if (active) {
    const v8h* wr0 = (const v8h*)&wp2[(d * 84 + (2 * p) * 21 + u) * 24];
    const v8h* wr1 = (const v8h*)&wp2[(d * 84 + (2 * p + 1) * 21 + u) * 24];
#pragma unroll
    for (int ch = 0; ch < 3; ++ch) {
      v8h a = wr0[ch], b = wr1[ch];
#pragma unroll
      for (int q = 0; q < 4; ++q) {
        v2f16 t0; t0[0] = a[2 * q]; t0[1] = a[2 * q + 1]; w0[ch * 4 + q] = t0;
        v2f16 t1; t1[0] = b[2 * q]; t1[1] = b[2 * q + 1]; w1[ch * 4 + q] = t1;
      }
    }
  }
  // unit-major pre2: gates (2p, 2p+1) of unit u are ADJACENT columns
  const int cp = d * 84 + u * 4 + 2 * p;
  const ptrdiff_t dlt = (ptrdiff_t)(d ? -nb : nb) * 176;
  const _Float16* pp = pre2 + ((size_t)(d ? 1023 : 0) * (size_t)nb + bl) * 176;

  // 8-deep prefetch pipeline: one v2f16 per step
  v2f16 pa = *(const v2f16*)(pp + cp);
  v2f16 pb = *(const v2f16*)(pp + dlt + cp);
  v2f16 pc = *(const v2f16*)(pp + 2 * dlt + cp);
  v2f16 pd = *(const v2f16*)(pp + 3 * dlt + cp);
  v2f16 pe = *(const v2f16*)(pp + 4 * dlt + cp);
  v2f16 pg = *(const v2f16*)(pp + 5 * dlt + cp);
  v2f16 ph = *(const v2f16*)(pp + 6 * dlt + cp);
  v2f16 pi = *(const v2f16*)(pp + 7 * dlt + cp);
  const _Float16* pf = pp + 8 * dlt;

  float cc = 0.f;
  int s = 0;

#define L2STEP(P)                                                           \
  {                                                                         \
    const int cur = s & 1, nxt = cur ^ 1;                                   \
    float A0v = (float)P[0], A1v = (float)P[1];                             \
    const float4* kp = (const float4*)&kv[cur][0];                          \
    float4 q0 = kp[0], q1 = kp[1], q2 = kp[2];                              \
    __builtin_amdgcn_s_setprio(1);                                          \
    float x0 = A0v, x1 = 0.f, x2 = 0.f, x3 = 0.f;                           \
    float z0 = A1v, z1 = 0.f, z2 = 0.f, z3 = 0.f;                           \
    x0 = fdot2(__builtin_bit_cast(v2f16, q0.x), w0[0], x0);                 \
    x1 = fdot2(__builtin_bit_cast(v2f16, q0.y), w0[1], x1);                 \
    x2 = fdot2(__builtin_bit_cast(v2f16, q0.z), w0[2], x2);                 \
    x3 = fdot2(__builtin_bit_cast(v2f16, q0.w), w0[3], x3);                 \
    x0 = fdot2(__builtin_bit_cast(v2f16, q1.x), w0[4], x0);                 \
    x1 = fdot2(__builtin_bit_cast(v2f16, q1.y), w0[5], x1);                 \
    x2 = fdot2(__builtin_bit_cast(v2f16, q1.z), w0[6], x2);                 \
    x3 = fdot2(__builtin_bit_cast(v2f16, q1.w), w0[7], x3);                 \
    x0 = fdot2(__builtin_bit_cast(v2f16, q2.x), w0[8], x0);                 \
    x1 = fdot2(__builtin_bit_cast(v2f16, q2.y), w0[9], x1);                 \
    x2 = fdot2(__builtin_bit_cast(v2f16, q2.z), w0[10], x2);                \
    x3 = fdot2(__builtin_bit_cast(v2f16, q2.w), w0[11], x3);                \
    z0 = fdot2(__builtin_bit_cast(v2f16, q0.x), w1[0], z0);                 \
    z1 = fdot2(__builtin_bit_cast(v2f16, q0.y), w1[1], z1);                 \
    z2 = fdot2(__builtin_bit_cast(v2f16, q0.z), w1[2], z2);                 \
    z3 = fdot2(__builtin_bit_cast(v2f16, q0.w), w1[3], z3);                 \
    z0 = fdot2(__builtin_bit_cast(v2f16, q1.x), w1[4], z0);                 \
    z1 = fdot2(__builtin_bit_cast(v2f16, q1.y), w1[5], z1);                 \
    z2 = fdot2(__builtin_bit_cast(v2f16, q1.z), w1[6], z2);                 \
    z3 = fdot2(__builtin_bit_cast(v2f16, q1.w), w1[7], z3);                 \
    z0 = fdot2(__builtin_bit_cast(v2f16, q2.x), w1[8], z0);                 \
    z1 = fdot2(__builtin_bit_cast(v2f16, q2.y), w1[9], z1);                 \
    z2 = fdot2(__builtin_bit_cast(v2f16, q2.z), w1[10], z2);                \
    z3 = fdot2(__builtin_bit_cast(v2f16, q2.w), w1[11], z3);                \
    float A = (x0 + x1) + (x2 + x3), Bv = (z0 + z1) + (z2 + z3);            \
    /* row0 = gate 2p (p=0: i sigm, p=1: g tanh); row1 = f/o sigm */        \
    float r0v = rcpf(1.f + ex2(-A));                                        \
    float Y0 = p ? fmaf(2.f, r0v, -1.f) : r0v;                              \
    float Y1 = rcpf(1.f + ex2(-Bv));                                        \
    float Zs = dpp_xor1(Y0);                                                \
    float Ws = dpp_xor1(Y1);                                                \
    float ai = p ? Zs : Y0;                                                 \
    float af = p ? Ws : Y1;                                                 \
    float ag = p ? Y0 : Zs;                                                 \
    float ao = p ? Y1 : Ws;                                                 \
    cc = fmaf(af, cc, ai * ag);                                             \
    float tc = fmaf(2.f, rcpf(1.f + ex2(cc * -LOG2E2)), -1.f);              \
    float hv = ao * tc;                                                     \
    __builtin_amdgcn_s_setprio(0);                                          \
    if (active && p == 0) {                                                 \
      _Float16 hh = (_Float16)hv;                                           \
      int te = d ? (1023 - s) : s;                                          \
      kv[nxt][u] = hh;                                                      \
      h2[((size_t)te * nb + bl) * 48 + d * 21 + u] = hh;                    \
    }                                                                       \
    if (s < 1016) P = *(const v2f16*)(pf + cp);                             \
    pf += dlt;                                                              \
    ++s;                                                                    \
  }

#pragma unroll 1
  for (int it = 0; it < 128; ++it) {
    L2STEP(pa)
    L2STEP(pb)
    L2STEP(pc)
    L2STEP(pd)
    L2STEP(pe)
    L2STEP(pg)
    L2STEP(ph)
    L2STEP(pi)
  }
#undef L2STEP
}

// ---------------------------------------------------------------------------
// K4: dense head. local row = t*nb+bl -> out[(b0+bl)*1024 + t].
// ---------------------------------------------------------------------------
__global__ __launch_bounds__(256) void head_kernel(
    const _Float16* __restrict__ h2,
    const float* __restrict__ d1w, const float* __restrict__ d1b,
    const float* __restrict__ d2w, const float* __restrict__ d2b,
    const float* __restrict__ ow, const float* __restrict__ ob,
    float* __restrict__ out, int b0, int lognb) {
  int n = blockIdx.x * 256 + threadIdx.x;
  int t = n >> lognb, bl = n & ((1 << lognb) - 1);
  const v8h* hp = (const v8h*)&h2[(size_t)n * 48];
  float in[48];
#pragma unroll
  for (int i = 0; i < 6; ++i) {
    v8h hc = hp[i];
#pragma unroll
    for (int j = 0; j < 8; ++j) in[i * 8 + j] = (float)hc[j];
  }
  float a1[30];
#pragma unroll
  for (int cc = 0; cc < 30; ++cc) {
    float a = d1b[cc];
#pragma unroll
    for (int k = 0; k < 42; ++k) a += in[k] * d1w[cc * 42 + k];
    a1[cc] = fmaxf(a, 0.f);
  }
  float a2[20];
#pragma unroll
  for (int cc = 0; cc < 20; ++cc) {
    float a = d2b[cc];
#pragma unroll
    for (int k = 0; k < 30; ++k) a += a1[k] * d2w[cc * 30 + k];
    a2[cc] = fmaxf(a, 0.f);
  }
  float o = ob[0];
#pragma unroll
  for (int k = 0; k < 20; ++k) o += a2[k] * ow[k];
  out[(size_t)(b0 + bl) * 1024 + t] = o;
}

// ---------------------------------------------------------------------------
extern "C" void kernel_launch(void* const* d_in, const int* in_sizes, int n_in,
                              void* d_out, int out_size, void* d_ws, size_t ws_size,
                              hipStream_t stream) {
  const float* x = (const float*)d_in[0];
  const float* wih1f = (const float*)d_in[1];
  const float* whh1f = (const float*)d_in[2];
  const float* bih1f = (const float*)d_in[3];
  const float* bhh1f = (const float*)d_in[4];
  const float* wih1b = (const float*)d_in[5];
  const float* whh1b = (const float*)d_in[6];
  const float* bih1b = (const float*)d_in[7];
  const float* bhh1b = (const float*)d_in[8];
  const float* wih2f = (const float*)d_in[9];
  const float* whh2f = (const float*)d_in[10];
  const float* bih2f = (const float*)d_in[11];
  const float* bhh2f = (const float*)d_in[12];
  const float* wih2b = (const float*)d_in[13];
  const float* whh2b = (const float*)d_in[14];
  const float* bih2b = (const float*)d_in[15];
  const float* bhh2b = (const float*)d_in[16];
  const float* d1w = (const float*)d_in[17];
  const float* d1b = (const float*)d_in[18];
  const float* d2w = (const float*)d_in[19];
  const float* d2b = (const float*)d_in[20];
  const float* ow = (const float*)d_in[21];
  const float* ob = (const float*)d_in[22];
  float* out = (float*)d_out;
  char* wsb = (char*)d_ws;

  // adaptive batch slicing: per-slice bytes = rows*(352 + 96), rows = nb*1024
  const int cands[6] = {1, 2, 4, 8, 16, 32};
  int nslice = 32;
  for (int i = 0; i < 6; ++i) {
    size_t rows = (size_t)(512 / cands[i]) * 1024;
    if (O_DATA + rows * 448 <= ws_size) { nslice = cands[i]; break; }
  }
  const int nb = 512 / nslice;
  int lognb = 0; while ((1 << lognb) < nb) ++lognb;
  const size_t rows = (size_t)nb * 1024;

  _Float16* w1m = (_Float16*)(wsb + O_W1M);
  _Float16* wp2 = (_Float16*)(wsb + O_WP2);
  _Float16* h1  = (_Float16*)(wsb + O_DATA);          // becomes pre2 in place
  _Float16* h2  = (_Float16*)(wsb + O_DATA + rows * 352);

  pack_kernel<<<348, 256, 0, stream>>>(wih1f, whh1f, wih1b, whh1b,
                                       bih1f, bhh1f, bih1b, bhh1b,
                                       wih2f, wih2b, whh2f, whh2b,
                                       bih2f, bhh2f, bih2b, bhh2b, wsb);

  for (int s = 0; s < nslice; ++s) {
    const int b0 = s * nb;
    lstm1_kernel<<<dim3(nb / 16, 2), 1024, 0, stream>>>(x, w1m, h1, b0, nb);
    pre2_kernel<<<nb * 16, 256, 0, stream>>>(h1, wsb);
    lstm2_kernel<<<dim3(nb, 2), 64, 0, stream>>>(h1, wp2, h2, nb);
    head_kernel<<<nb * 4, 256, 0, stream>>>(h2, d1w, d1b, d2w, d2b, ow, ob,
                                            out, b0, lognb);
  }
}